// Round 5
// baseline (130.979 us; speedup 1.0000x reference)
//
#include <hip/hip_runtime.h>
#include <hip/hip_bf16.h>

#define F 64
#define C 128
#define SPAN 128          // rows per wave
#define NT (SPAN / 16)    // 8 sixteen-row MFMA tiles per wave

typedef __attribute__((ext_vector_type(8))) short short8;
typedef __attribute__((ext_vector_type(4))) float floatx4;

__device__ __forceinline__ unsigned short f32_to_bf16_rne(float f) {
    unsigned int u = __builtin_bit_cast(unsigned int, f);
    unsigned int r = u + 0x7FFFu + ((u >> 16) & 1u);
    return (unsigned short)(r >> 16);
}

// compiler lowers pairs of these to v_cvt_pk_bf16_f32 (m240)
__device__ __forceinline__ short bf16c(float f) {
    return __builtin_bit_cast(short, __float2bfloat16(f));
}

__device__ __forceinline__ float fast_sigmoid(float v) {
    float e = __builtin_amdgcn_exp2f(v * -1.44269504088896f);
    return __builtin_amdgcn_rcpf(1.0f + e);
}

// Zero d_out (blocks 0..Z-1) + build per-lane bf16 W fragments in d_ws (last block).
// Entry idx = (nf*2+ks)*64 + lane, 8 bf16 each; col = nf*16+(lane&15),
// k = ks*32 + (lane>>4)*8 + e  (same k-mapping as the A-fragment load).
__global__ __launch_bounds__(256) void prep_kernel(
    const float* __restrict__ w, float* __restrict__ out,
    unsigned short* __restrict__ wsfrag, int out_f4)
{
    const int b = blockIdx.x;
    if (b < (int)gridDim.x - 1) {
        int idx = b * 256 + threadIdx.x;
        if (idx < out_f4) ((float4*)out)[idx] = make_float4(0.f, 0.f, 0.f, 0.f);
    } else {
        #pragma unroll
        for (int i = 0; i < 4; ++i) {
            int idx = threadIdx.x * 4 + i;            // 0..1023
            int lane = idx & 63;
            int ks   = (idx >> 6) & 1;
            int nf   = idx >> 7;                      // 0..7
            int col  = nf * 16 + (lane & 15);
            int kg   = (lane >> 4) * 8;
            unsigned short* dst = wsfrag + (size_t)idx * 8;
            #pragma unroll
            for (int e = 0; e < 8; ++e) {
                int k = ks * 32 + kg + e;
                dst[e] = f32_to_bf16_rne(w[k * C + col]);
            }
        }
    }
}

// LDS-free X path: each wave streams 128 rows as 8 x 16-row tiles, A-fragments
// straight from global (wave's 64x16B = contiguous 4KB), depth-2 prefetch.
// W fragments live in LDS (16KB, staged once, conflict-free lane-contiguous
// ds_read_b128) to keep VGPR <= 128 -> 4 waves/SIMD.
__global__ __launch_bounds__(256, 4) void fused_seg_gemm(
    const float* __restrict__ x, const unsigned short* __restrict__ wsfrag,
    const int* __restrict__ seg, float* __restrict__ out)
{
    __shared__ unsigned short wlds[16 * 64 * 8];     // 16 KB: [(nf*2+ks)*64+lane]*8

    const int tid  = threadIdx.x;
    const int lane = tid & 63;
    const int wave = tid >> 6;
    const int l15  = lane & 15;
    const int g    = lane >> 4;
    const long long base = ((long long)blockIdx.x * 4 + wave) * SPAN;

    // ---- stage W frags to LDS: 1024 x 16B, coalesced, once per block ----
    {
        const short8* fb = (const short8*)wsfrag;
        short8* fl = (short8*)wlds;
        #pragma unroll
        for (int i = 0; i < 4; ++i) fl[tid + i * 256] = fb[tid + i * 256];
    }

    // seg for the whole 128-row span: 2 regs, extracted per tile by shuffle
    int sg0 = seg[base + lane];        // rows 0..63
    int sg1 = seg[base + 64 + lane];   // rows 64..127

    const float4* xp = (const float4*)(x + base * F);
    const int fi = l15 * 16 + g * 2;   // A-frag float4 index (+1 hi, +8 ks1)

    float runsum[8];
    #pragma unroll
    for (int nf = 0; nf < 8; ++nf) runsum[nf] = 0.0f;
    int cur_seg = -1;

    auto flush = [&]() {
        if (cur_seg >= 0) {
            #pragma unroll
            for (int nf = 0; nf < 8; ++nf) {
                float v = runsum[nf];
                v += __shfl_xor(v, 16);
                v += __shfl_xor(v, 32);
                if (lane < 16) atomicAdd(&out[cur_seg * C + nf * 16 + lane], v);
                runsum[nf] = 0.0f;
            }
        }
        cur_seg = -1;
    };

    float4 bufA[4], bufB[4];
    #define ISSUE(B, T) { const int o = fi + (T) * 256; \
        B[0] = xp[o]; B[1] = xp[o + 1]; B[2] = xp[o + 8]; B[3] = xp[o + 9]; }

    ISSUE(bufA, 0);
    ISSUE(bufB, 1);
    __syncthreads();   // W staged (x loads for tiles 0,1 already in flight)

    auto step = [&](float4* buf, int t) {
        // ---- convert tile t (waits on its loads), then reuse slot for t+2 ----
        short8 a0, a1;
        a0[0] = bf16c(buf[0].x); a0[1] = bf16c(buf[0].y); a0[2] = bf16c(buf[0].z); a0[3] = bf16c(buf[0].w);
        a0[4] = bf16c(buf[1].x); a0[5] = bf16c(buf[1].y); a0[6] = bf16c(buf[1].z); a0[7] = bf16c(buf[1].w);
        a1[0] = bf16c(buf[2].x); a1[1] = bf16c(buf[2].y); a1[2] = bf16c(buf[2].z); a1[3] = bf16c(buf[2].w);
        a1[4] = bf16c(buf[3].x); a1[5] = bf16c(buf[3].y); a1[6] = bf16c(buf[3].z); a1[7] = bf16c(buf[3].w);
        if (t + 2 < NT) ISSUE(buf, t + 2);   // depth-2: covered by ~2 compute phases

        // ---- 16 MFMAs, B-frags from LDS (lane-contiguous b128, conflict-free) ----
        const short8* bl = (const short8*)wlds;
        floatx4 acc[8];
        #pragma unroll
        for (int nf = 0; nf < 8; ++nf) {
            short8 b0 = bl[(nf * 2 + 0) * 64 + lane];
            short8 b1 = bl[(nf * 2 + 1) * 64 + lane];
            acc[nf] = (floatx4)0.0f;
            acc[nf] = __builtin_amdgcn_mfma_f32_16x16x32_bf16(a0, b0, acc[nf], 0, 0, 0);
            acc[nf] = __builtin_amdgcn_mfma_f32_16x16x32_bf16(a1, b1, acc[nf], 0, 0, 0);
        }

        // ---- sigmoid + segmented accumulate ----
        // C/D (m89): col = nf*16 + l15, tile-row = g*4 + r
        const int sreg = (t < 4) ? sg0 : sg1;
        const int tb   = (t & 3) * 16;
        const int u0 = __shfl(sreg, tb), u15 = __shfl(sreg, tb + 15);
        if (u0 == u15) {                       // uniform tile (~94%), wave-uniform branch
            if (u0 != cur_seg) { flush(); cur_seg = u0; }
            #pragma unroll
            for (int nf = 0; nf < 8; ++nf)
                #pragma unroll
                for (int r = 0; r < 4; ++r)
                    runsum[nf] += fast_sigmoid(acc[nf][r]);
        } else {                               // boundary tile: per-lane monotone walk
            flush();
            const int sr0 = __shfl(sreg, tb + g * 4 + 0), sr1 = __shfl(sreg, tb + g * 4 + 1);
            const int sr2 = __shfl(sreg, tb + g * 4 + 2), sr3 = __shfl(sreg, tb + g * 4 + 3);
            #pragma unroll
            for (int nf = 0; nf < 8; ++nf) {
                const int col = nf * 16 + l15;
                float run = fast_sigmoid(acc[nf][0]);
                int   rs  = sr0;
                float v;
                v = fast_sigmoid(acc[nf][1]);
                if (sr1 != rs) { atomicAdd(&out[rs * C + col], run); rs = sr1; run = v; } else run += v;
                v = fast_sigmoid(acc[nf][2]);
                if (sr2 != rs) { atomicAdd(&out[rs * C + col], run); rs = sr2; run = v; } else run += v;
                v = fast_sigmoid(acc[nf][3]);
                if (sr3 != rs) { atomicAdd(&out[rs * C + col], run); rs = sr3; run = v; } else run += v;
                atomicAdd(&out[rs * C + col], run);
            }
        }
    };

    step(bufA, 0); step(bufB, 1); step(bufA, 2); step(bufB, 3);
    step(bufA, 4); step(bufB, 5); step(bufA, 6); step(bufB, 7);
    flush();
    #undef ISSUE
}

extern "C" void kernel_launch(void* const* d_in, const int* in_sizes, int n_in,
                              void* d_out, int out_size, void* d_ws, size_t ws_size,
                              hipStream_t stream) {
    const float* x  = (const float*)d_in[0];
    const float* w  = (const float*)d_in[1];
    const int* seg  = (const int*)d_in[2];
    float* out      = (float*)d_out;

    const int n = in_sizes[0] / F;                    // 1048576
    const int nblocks = n / (4 * SPAN);               // 2048 blocks x 4 waves x 128 rows

    const int out_f4 = out_size / 4;
    const int zblocks = (out_f4 + 255) / 256;

    prep_kernel<<<zblocks + 1, 256, 0, stream>>>(
        w, out, (unsigned short*)d_ws, out_f4);

    fused_seg_gemm<<<nblocks, 256, 0, stream>>>(
        x, (const unsigned short*)d_ws, seg, out);
}

// Round 7
// 128.506 us; speedup vs baseline: 1.0192x; 1.0192x over previous
//
#include <hip/hip_runtime.h>
#include <hip/hip_bf16.h>

#define F 64
#define C 128
#define SPAN 128          // rows per wave
#define NT (SPAN / 16)    // 8 sixteen-row MFMA tiles per wave

typedef __attribute__((ext_vector_type(8))) short short8;
typedef __attribute__((ext_vector_type(4))) float floatx4;

__device__ __forceinline__ unsigned short f32_to_bf16_rne(float f) {
    unsigned int u = __builtin_bit_cast(unsigned int, f);
    unsigned int r = u + 0x7FFFu + ((u >> 16) & 1u);
    return (unsigned short)(r >> 16);
}

// compiler lowers pairs of these to v_cvt_pk_bf16_f32 (m240)
__device__ __forceinline__ short bf16c(float f) {
    return __builtin_bit_cast(short, __float2bfloat16(f));
}

__device__ __forceinline__ float fast_sigmoid(float v) {
    float e = __builtin_amdgcn_exp2f(v * -1.44269504088896f);
    return __builtin_amdgcn_rcpf(1.0f + e);
}

// Zero d_out (blocks 0..Z-1) + build per-lane bf16 W fragments in d_ws (last block).
// Entry idx = (nf*2+ks)*64 + lane, 8 bf16 each; col = nf*16+(lane&15),
// k = ks*32 + (lane>>4)*8 + e  (same k-mapping as the A-fragment load).
__global__ __launch_bounds__(256) void prep_kernel(
    const float* __restrict__ w, float* __restrict__ out,
    unsigned short* __restrict__ wsfrag, int out_f4)
{
    const int b = blockIdx.x;
    if (b < (int)gridDim.x - 1) {
        int idx = b * 256 + threadIdx.x;
        if (idx < out_f4) ((float4*)out)[idx] = make_float4(0.f, 0.f, 0.f, 0.f);
    } else {
        #pragma unroll
        for (int i = 0; i < 4; ++i) {
            int idx = threadIdx.x * 4 + i;            // 0..1023
            int lane = idx & 63;
            int ks   = (idx >> 6) & 1;
            int nf   = idx >> 7;                      // 0..7
            int col  = nf * 16 + (lane & 15);
            int kg   = (lane >> 4) * 8;
            unsigned short* dst = wsfrag + (size_t)idx * 8;
            #pragma unroll
            for (int e = 0; e < 8; ++e) {
                int k = ks * 32 + kg + e;
                dst[e] = f32_to_bf16_rne(w[k * C + col]);
            }
        }
    }
}

// LDS-free X path: each wave streams 128 rows as 8 x 16-row tiles, A-fragments
// straight from global (wave's 64x16B = contiguous 4KB), depth-2 prefetch via
// two sets of NAMED float4 buffers passed as separate macro args (no
// address-taken arrays -> SROA keeps them in VGPRs; R5's pointer-passing
// demoted them to scratch = 2x regression; R6's B##0 paste didn't lex).
// W fragments in LDS (16KB, conflict-free lane-contiguous ds_read_b128).
__global__ __launch_bounds__(256, 4) void fused_seg_gemm(
    const float* __restrict__ x, const unsigned short* __restrict__ wsfrag,
    const int* __restrict__ seg, float* __restrict__ out)
{
    __shared__ unsigned short wlds[16 * 64 * 8];     // 16 KB: [(nf*2+ks)*64+lane]*8

    const int tid  = threadIdx.x;
    const int lane = tid & 63;
    const int wave = tid >> 6;
    const int l15  = lane & 15;
    const int g    = lane >> 4;
    const long long base = ((long long)blockIdx.x * 4 + wave) * SPAN;

    // ---- stage W frags to LDS: 1024 x 16B, coalesced, once per block ----
    {
        const short8* fb = (const short8*)wsfrag;
        short8* fl = (short8*)wlds;
        #pragma unroll
        for (int i = 0; i < 4; ++i) fl[tid + i * 256] = fb[tid + i * 256];
    }

    // seg for the whole 128-row span: 2 regs, extracted per tile by shuffle
    int sg0 = seg[base + lane];        // rows 0..63
    int sg1 = seg[base + 64 + lane];   // rows 64..127

    const float4* xp = (const float4*)(x + base * F);
    const int fi = l15 * 16 + g * 2;   // A-frag float4 index (+1 hi, +8 ks1)

    float runsum[8];
    #pragma unroll
    for (int nf = 0; nf < 8; ++nf) runsum[nf] = 0.0f;
    int cur_seg = -1;

    auto flush = [&]() {
        if (cur_seg >= 0) {
            #pragma unroll
            for (int nf = 0; nf < 8; ++nf) {
                float v = runsum[nf];
                v += __shfl_xor(v, 16);
                v += __shfl_xor(v, 32);
                if (lane < 16) atomicAdd(&out[cur_seg * C + nf * 16 + lane], v);
                runsum[nf] = 0.0f;
            }
        }
        cur_seg = -1;
    };

    float4 bufA0, bufA1, bufA2, bufA3;   // named scalars: never address-taken
    float4 bufB0, bufB1, bufB2, bufB3;

#define ISSUE(B0, B1, B2, B3, T) { const int o_ = fi + (T) * 256; \
        B0 = xp[o_]; B1 = xp[o_ + 1]; B2 = xp[o_ + 8]; B3 = xp[o_ + 9]; }

#define STEP(B0, B1, B2, B3, T) { \
        short8 a0, a1; \
        a0[0] = bf16c(B0.x); a0[1] = bf16c(B0.y); a0[2] = bf16c(B0.z); a0[3] = bf16c(B0.w); \
        a0[4] = bf16c(B1.x); a0[5] = bf16c(B1.y); a0[6] = bf16c(B1.z); a0[7] = bf16c(B1.w); \
        a1[0] = bf16c(B2.x); a1[1] = bf16c(B2.y); a1[2] = bf16c(B2.z); a1[3] = bf16c(B2.w); \
        a1[4] = bf16c(B3.x); a1[5] = bf16c(B3.y); a1[6] = bf16c(B3.z); a1[7] = bf16c(B3.w); \
        if ((T) + 2 < NT) ISSUE(B0, B1, B2, B3, (T) + 2)  /* depth-2 prefetch */ \
        const short8* bl_ = (const short8*)wlds; \
        floatx4 acc[8]; \
        _Pragma("unroll") \
        for (int nf = 0; nf < 8; ++nf) { \
            short8 b0 = bl_[(nf * 2 + 0) * 64 + lane]; \
            short8 b1 = bl_[(nf * 2 + 1) * 64 + lane]; \
            acc[nf] = (floatx4)0.0f; \
            acc[nf] = __builtin_amdgcn_mfma_f32_16x16x32_bf16(a0, b0, acc[nf], 0, 0, 0); \
            acc[nf] = __builtin_amdgcn_mfma_f32_16x16x32_bf16(a1, b1, acc[nf], 0, 0, 0); \
        } \
        /* C/D (m89): col = nf*16 + l15, tile-row = g*4 + r */ \
        const int sreg = ((T) < 4) ? sg0 : sg1; \
        const int tb   = ((T) & 3) * 16; \
        const int u0 = __shfl(sreg, tb), u15 = __shfl(sreg, tb + 15); \
        if (u0 == u15) {                       /* uniform tile (~94%) */ \
            if (u0 != cur_seg) { flush(); cur_seg = u0; } \
            _Pragma("unroll") \
            for (int nf = 0; nf < 8; ++nf) \
                _Pragma("unroll") \
                for (int r = 0; r < 4; ++r) \
                    runsum[nf] += fast_sigmoid(acc[nf][r]); \
        } else {                               /* boundary tile: monotone walk */ \
            flush(); \
            const int sr0 = __shfl(sreg, tb + g * 4 + 0), sr1 = __shfl(sreg, tb + g * 4 + 1); \
            const int sr2 = __shfl(sreg, tb + g * 4 + 2), sr3 = __shfl(sreg, tb + g * 4 + 3); \
            _Pragma("unroll") \
            for (int nf = 0; nf < 8; ++nf) { \
                const int col = nf * 16 + l15; \
                float run = fast_sigmoid(acc[nf][0]); \
                int   rs  = sr0; \
                float v; \
                v = fast_sigmoid(acc[nf][1]); \
                if (sr1 != rs) { atomicAdd(&out[rs * C + col], run); rs = sr1; run = v; } else run += v; \
                v = fast_sigmoid(acc[nf][2]); \
                if (sr2 != rs) { atomicAdd(&out[rs * C + col], run); rs = sr2; run = v; } else run += v; \
                v = fast_sigmoid(acc[nf][3]); \
                if (sr3 != rs) { atomicAdd(&out[rs * C + col], run); rs = sr3; run = v; } else run += v; \
                atomicAdd(&out[rs * C + col], run); \
            } \
        } \
    }

    ISSUE(bufA0, bufA1, bufA2, bufA3, 0)
    ISSUE(bufB0, bufB1, bufB2, bufB3, 1)
    __syncthreads();   // W staged (x loads for tiles 0,1 already in flight)

    STEP(bufA0, bufA1, bufA2, bufA3, 0)
    STEP(bufB0, bufB1, bufB2, bufB3, 1)
    STEP(bufA0, bufA1, bufA2, bufA3, 2)
    STEP(bufB0, bufB1, bufB2, bufB3, 3)
    STEP(bufA0, bufA1, bufA2, bufA3, 4)
    STEP(bufB0, bufB1, bufB2, bufB3, 5)
    STEP(bufA0, bufA1, bufA2, bufA3, 6)
    STEP(bufB0, bufB1, bufB2, bufB3, 7)
    flush();
#undef ISSUE
#undef STEP
}

extern "C" void kernel_launch(void* const* d_in, const int* in_sizes, int n_in,
                              void* d_out, int out_size, void* d_ws, size_t ws_size,
                              hipStream_t stream) {
    const float* x  = (const float*)d_in[0];
    const float* w  = (const float*)d_in[1];
    const int* seg  = (const int*)d_in[2];
    float* out      = (float*)d_out;

    const int n = in_sizes[0] / F;                    // 1048576
    const int nblocks = n / (4 * SPAN);               // 2048 blocks x 4 waves x 128 rows

    const int out_f4 = out_size / 4;
    const int zblocks = (out_f4 + 255) / 256;

    prep_kernel<<<zblocks + 1, 256, 0, stream>>>(
        w, out, (unsigned short*)d_ws, out_f4);

    fused_seg_gemm<<<nblocks, 256, 0, stream>>>(
        x, (const unsigned short*)d_ws, seg, out);
}

// Round 8
// 62.550 us; speedup vs baseline: 2.0940x; 2.0544x over previous
//
#include <hip/hip_runtime.h>
#include <hip/hip_bf16.h>

#define F 64
#define C 128
#define SPAN 128          // rows per wave
#define NT (SPAN / 16)    // 8 sixteen-row MFMA tiles per wave

typedef __attribute__((ext_vector_type(8))) short short8;
typedef __attribute__((ext_vector_type(4))) float floatx4;

__device__ __forceinline__ unsigned short f32_to_bf16_rne(float f) {
    unsigned int u = __builtin_bit_cast(unsigned int, f);
    unsigned int r = u + 0x7FFFu + ((u >> 16) & 1u);
    return (unsigned short)(r >> 16);
}

// compiler lowers pairs of these to v_cvt_pk_bf16_f32 (m240)
__device__ __forceinline__ short bf16c(float f) {
    return __builtin_bit_cast(short, __float2bfloat16(f));
}

__device__ __forceinline__ float fast_sigmoid(float v) {
    float e = __builtin_amdgcn_exp2f(v * -1.44269504088896f);
    return __builtin_amdgcn_rcpf(1.0f + e);
}

// Zero d_out (blocks 0..Z-1) + build per-lane bf16 W fragments in d_ws (last block).
// Entry idx = (nf*2+ks)*64 + lane, 8 bf16 each; col = nf*16+(lane&15),
// k = ks*32 + (lane>>4)*8 + e  (same k-mapping as the A-fragment load).
__global__ __launch_bounds__(256) void prep_kernel(
    const float* __restrict__ w, float* __restrict__ out,
    unsigned short* __restrict__ wsfrag, int out_f4)
{
    const int b = blockIdx.x;
    if (b < (int)gridDim.x - 1) {
        int idx = b * 256 + threadIdx.x;
        if (idx < out_f4) ((float4*)out)[idx] = make_float4(0.f, 0.f, 0.f, 0.f);
    } else {
        #pragma unroll
        for (int i = 0; i < 4; ++i) {
            int idx = threadIdx.x * 4 + i;            // 0..1023
            int lane = idx & 63;
            int ks   = (idx >> 6) & 1;
            int nf   = idx >> 7;                      // 0..7
            int col  = nf * 16 + (lane & 15);
            int kg   = (lane >> 4) * 8;
            unsigned short* dst = wsfrag + (size_t)idx * 8;
            #pragma unroll
            for (int e = 0; e < 8; ++e) {
                int k = ks * 32 + kg + e;
                dst[e] = f32_to_bf16_rne(w[k * C + col]);
            }
        }
    }
}

// Same structure as R7; ONLY change: __launch_bounds__(256,4) -> (256,3).
// Theory: the 128-VGPR cap of (,4) forced full scratch spill (R5 profile:
// VGPR_Count=64 @ 1.4TB/s); live set is ~120-135 regs, cap ~170 of (,3) fits.
__global__ __launch_bounds__(256, 3) void fused_seg_gemm(
    const float* __restrict__ x, const unsigned short* __restrict__ wsfrag,
    const int* __restrict__ seg, float* __restrict__ out)
{
    __shared__ unsigned short wlds[16 * 64 * 8];     // 16 KB: [(nf*2+ks)*64+lane]*8

    const int tid  = threadIdx.x;
    const int lane = tid & 63;
    const int wave = tid >> 6;
    const int l15  = lane & 15;
    const int g    = lane >> 4;
    const long long base = ((long long)blockIdx.x * 4 + wave) * SPAN;

    // ---- stage W frags to LDS: 1024 x 16B, coalesced, once per block ----
    {
        const short8* fb = (const short8*)wsfrag;
        short8* fl = (short8*)wlds;
        #pragma unroll
        for (int i = 0; i < 4; ++i) fl[tid + i * 256] = fb[tid + i * 256];
    }

    // seg for the whole 128-row span: 2 regs, extracted per tile by shuffle
    int sg0 = seg[base + lane];        // rows 0..63
    int sg1 = seg[base + 64 + lane];   // rows 64..127

    const float4* xp = (const float4*)(x + base * F);
    const int fi = l15 * 16 + g * 2;   // A-frag float4 index (+1 hi, +8 ks1)

    float runsum[8];
    #pragma unroll
    for (int nf = 0; nf < 8; ++nf) runsum[nf] = 0.0f;
    int cur_seg = -1;

    auto flush = [&]() {
        if (cur_seg >= 0) {
            #pragma unroll
            for (int nf = 0; nf < 8; ++nf) {
                float v = runsum[nf];
                v += __shfl_xor(v, 16);
                v += __shfl_xor(v, 32);
                if (lane < 16) atomicAdd(&out[cur_seg * C + nf * 16 + lane], v);
                runsum[nf] = 0.0f;
            }
        }
        cur_seg = -1;
    };

    float4 bufA0, bufA1, bufA2, bufA3;   // named scalars: never address-taken
    float4 bufB0, bufB1, bufB2, bufB3;

#define ISSUE(B0, B1, B2, B3, T) { const int o_ = fi + (T) * 256; \
        B0 = xp[o_]; B1 = xp[o_ + 1]; B2 = xp[o_ + 8]; B3 = xp[o_ + 9]; }

#define STEP(B0, B1, B2, B3, T) { \
        short8 a0, a1; \
        a0[0] = bf16c(B0.x); a0[1] = bf16c(B0.y); a0[2] = bf16c(B0.z); a0[3] = bf16c(B0.w); \
        a0[4] = bf16c(B1.x); a0[5] = bf16c(B1.y); a0[6] = bf16c(B1.z); a0[7] = bf16c(B1.w); \
        a1[0] = bf16c(B2.x); a1[1] = bf16c(B2.y); a1[2] = bf16c(B2.z); a1[3] = bf16c(B2.w); \
        a1[4] = bf16c(B3.x); a1[5] = bf16c(B3.y); a1[6] = bf16c(B3.z); a1[7] = bf16c(B3.w); \
        if ((T) + 2 < NT) ISSUE(B0, B1, B2, B3, (T) + 2)  /* depth-2 prefetch */ \
        const short8* bl_ = (const short8*)wlds; \
        floatx4 acc[8]; \
        _Pragma("unroll") \
        for (int nf = 0; nf < 8; ++nf) { \
            short8 b0 = bl_[(nf * 2 + 0) * 64 + lane]; \
            short8 b1 = bl_[(nf * 2 + 1) * 64 + lane]; \
            acc[nf] = (floatx4)0.0f; \
            acc[nf] = __builtin_amdgcn_mfma_f32_16x16x32_bf16(a0, b0, acc[nf], 0, 0, 0); \
            acc[nf] = __builtin_amdgcn_mfma_f32_16x16x32_bf16(a1, b1, acc[nf], 0, 0, 0); \
        } \
        /* C/D (m89): col = nf*16 + l15, tile-row = g*4 + r */ \
        const int sreg = ((T) < 4) ? sg0 : sg1; \
        const int tb   = ((T) & 3) * 16; \
        const int u0 = __shfl(sreg, tb), u15 = __shfl(sreg, tb + 15); \
        if (u0 == u15) {                       /* uniform tile (~94%) */ \
            if (u0 != cur_seg) { flush(); cur_seg = u0; } \
            _Pragma("unroll") \
            for (int nf = 0; nf < 8; ++nf) \
                _Pragma("unroll") \
                for (int r = 0; r < 4; ++r) \
                    runsum[nf] += fast_sigmoid(acc[nf][r]); \
        } else {                               /* boundary tile: monotone walk */ \
            flush(); \
            const int sr0 = __shfl(sreg, tb + g * 4 + 0), sr1 = __shfl(sreg, tb + g * 4 + 1); \
            const int sr2 = __shfl(sreg, tb + g * 4 + 2), sr3 = __shfl(sreg, tb + g * 4 + 3); \
            _Pragma("unroll") \
            for (int nf = 0; nf < 8; ++nf) { \
                const int col = nf * 16 + l15; \
                float run = fast_sigmoid(acc[nf][0]); \
                int   rs  = sr0; \
                float v; \
                v = fast_sigmoid(acc[nf][1]); \
                if (sr1 != rs) { atomicAdd(&out[rs * C + col], run); rs = sr1; run = v; } else run += v; \
                v = fast_sigmoid(acc[nf][2]); \
                if (sr2 != rs) { atomicAdd(&out[rs * C + col], run); rs = sr2; run = v; } else run += v; \
                v = fast_sigmoid(acc[nf][3]); \
                if (sr3 != rs) { atomicAdd(&out[rs * C + col], run); rs = sr3; run = v; } else run += v; \
                atomicAdd(&out[rs * C + col], run); \
            } \
        } \
    }

    ISSUE(bufA0, bufA1, bufA2, bufA3, 0)
    ISSUE(bufB0, bufB1, bufB2, bufB3, 1)
    __syncthreads();   // W staged (x loads for tiles 0,1 already in flight)

    STEP(bufA0, bufA1, bufA2, bufA3, 0)
    STEP(bufB0, bufB1, bufB2, bufB3, 1)
    STEP(bufA0, bufA1, bufA2, bufA3, 2)
    STEP(bufB0, bufB1, bufB2, bufB3, 3)
    STEP(bufA0, bufA1, bufA2, bufA3, 4)
    STEP(bufB0, bufB1, bufB2, bufB3, 5)
    STEP(bufA0, bufA1, bufA2, bufA3, 6)
    STEP(bufB0, bufB1, bufB2, bufB3, 7)
    flush();
#undef ISSUE
#undef STEP
}

extern "C" void kernel_launch(void* const* d_in, const int* in_sizes, int n_in,
                              void* d_out, int out_size, void* d_ws, size_t ws_size,
                              hipStream_t stream) {
    const float* x  = (const float*)d_in[0];
    const float* w  = (const float*)d_in[1];
    const int* seg  = (const int*)d_in[2];
    float* out      = (float*)d_out;

    const int n = in_sizes[0] / F;                    // 1048576
    const int nblocks = n / (4 * SPAN);               // 2048 blocks x 4 waves x 128 rows

    const int out_f4 = out_size / 4;
    const int zblocks = (out_f4 + 255) / 256;

    prep_kernel<<<zblocks + 1, 256, 0, stream>>>(
        w, out, (unsigned short*)d_ws, out_f4);

    fused_seg_gemm<<<nblocks, 256, 0, stream>>>(
        x, (const unsigned short*)d_ws, seg, out);
}